// Round 3
// baseline (1349.999 us; speedup 1.0000x reference)
//
#include <hip/hip_runtime.h>

typedef unsigned short u16;
typedef unsigned int   u32;
typedef unsigned long long u64;
typedef __attribute__((ext_vector_type(8))) short short8;
typedef __attribute__((ext_vector_type(4))) float f32x4;

#define T_TOK 8192
#define DIM   1024
#define NEXP  8
#define NPAIR (T_TOK * 2)     // 16384 token-expert pairs
#define MAXTILES 136          // sum ceil(cnt_e/128) <= 135; 136 % 8 == 0
#define NGU (MAXTILES * 8)    // 1088 units per GEMM phase
#define PREP_UNITS 769        // 1 sort + 768 cast units (x, W1, W2: 256 each)
#define COMB_UNITS 1024       // 8 tokens each
#define GRID_BLKS 1024

__device__ __forceinline__ u16 f2bf(float f) {
  u32 u = __builtin_bit_cast(u32, f);
  u32 r = (u + 0x7fffu + ((u >> 16) & 1u)) >> 16;  // RNE
  return (u16)r;
}
__device__ __forceinline__ float bf2f(u16 b) {
  return __builtin_bit_cast(float, ((u32)b) << 16);
}

__device__ __forceinline__ void gl_lds16(const u16* g, u16* l) {
  __builtin_amdgcn_global_load_lds(
      (const __attribute__((address_space(1))) u32*)g,
      (__attribute__((address_space(3))) u32*)l,
      16, 0, 0);
}

// Device-scope (agent) atomics: cross-XCD visible (per-XCD L2s not coherent
// for plain loads -> spins MUST use agent-scope atomic loads, not volatile).
__device__ __forceinline__ int ag_add(int* p) {
  return __hip_atomic_fetch_add(p, 1, __ATOMIC_RELAXED, __HIP_MEMORY_SCOPE_AGENT);
}
__device__ __forceinline__ int ag_ld(int* p) {
  return __hip_atomic_load(p, __ATOMIC_RELAXED, __HIP_MEMORY_SCOPE_AGENT);
}

// Claim next work unit from queue q (block-uniform result via LDS broadcast).
// Leading __syncthreads also separates the previous unit's LDS use.
__device__ __forceinline__ int claim(int* q, int* shq) {
  __syncthreads();
  if (threadIdx.x == 0) *shq = ag_add(q);
  __syncthreads();
  return *shq;
}

// Block-wide gate: wait until *c >= target, then acquire-fence so subsequent
// plain loads see data flushed by producers' signal() fences.
__device__ __forceinline__ void gate_wait(int* c, int target) {
  if (threadIdx.x == 0)
    while (ag_ld(c) < target) __builtin_amdgcn_s_sleep(8);
  __syncthreads();
  __threadfence();
}

// Producer handoff: every thread flushes its stores (agent-scope release),
// then one thread bumps the counter. Consumer's gate_wait pairs with this.
__device__ __forceinline__ void signal(int* c) {
  __threadfence();
  __syncthreads();
  if (threadIdx.x == 0) ag_add(c);
}

// ---------------- grouped GEMM unit: O rows of one 128x128 tile -------------
// Identical inner structure to the verified R0/R2 kernel: 128x128x64 K-tiles,
// single-buffered 32KB LDS, XOR chunk swizzle (bank-conflict-free),
// global_load_lds width-16 staging, 16x16x32 bf16 MFMA, 4 waves, 4x4 frags.
// INPLACE (GEMM2): output y overwrites h's SAME rows; safe because we wait
// for all 8 sibling units (same slot, all n0) to finish READING h via the
// per-slot rdone barrier before any epilogue store.
template <bool GATHER, bool INPLACE>
__device__ void gemm_unit(int slot, int n0, const u16* __restrict__ A,
                          const u16* __restrict__ W, u16* __restrict__ O,
                          const int* counts, const int* offsets,
                          const int* bucket, const int* tlist, int* rdone,
                          u16* As, u16* Bs) {
  const int info = tlist[slot];
  const int e    = info & 7;
  const int m0   = (info >> 3) << 7;
  const int cnt  = counts[e];
  const int seg  = offsets[e];

  const int tid  = threadIdx.x;
  const int lane = tid & 63;
  const int wave = tid >> 6;

  int aoff[4], boff[4];
#pragma unroll
  for (int j = 0; j < 4; ++j) {
    const int c   = ((wave << 2) + j) * 64 + lane;  // chunk 0..1023
    const int r   = c >> 3;                         // tile row
    const int c16 = (c & 7) ^ (r & 7);              // swizzled 16B chunk
    int p = seg + m0 + r;
    p = (p < seg + cnt) ? p : (seg + cnt - 1);      // clamp tail rows
    int rowbase;
    if (GATHER) { const int pair = bucket[p]; rowbase = (pair >> 1) * DIM; }
    else        { rowbase = p * DIM; }
    aoff[j] = rowbase + (c16 << 3);
    boff[j] = e * DIM * DIM + (n0 + r) * DIM + (c16 << 3);
  }

  f32x4 acc[4][4] = {};

  const int wm   = (wave >> 1) << 6;
  const int wn   = (wave & 1) << 6;
  const int lr   = lane & 15;
  const int quad = lane >> 4;

  for (int k0 = 0; k0 < DIM; k0 += 64) {
    __syncthreads();  // protect LDS reuse
#pragma unroll
    for (int j = 0; j < 4; ++j) {
      const int instr = (wave << 2) + j;
      gl_lds16(A + aoff[j] + k0, &As[instr << 9]);
      gl_lds16(W + boff[j] + k0, &Bs[instr << 9]);
    }
    __syncthreads();  // drains vmcnt for global_load_lds

#pragma unroll
    for (int kk = 0; kk < 64; kk += 32) {
      const int qb = (kk >> 3) + quad;
      short8 af[4], bf[4];
#pragma unroll
      for (int mi = 0; mi < 4; ++mi) {
        const int r = wm + (mi << 4) + lr;
        af[mi] = *(const short8*)&As[r * 64 + ((qb ^ (r & 7)) << 3)];
      }
#pragma unroll
      for (int ni = 0; ni < 4; ++ni) {
        const int r = wn + (ni << 4) + lr;
        bf[ni] = *(const short8*)&Bs[r * 64 + ((qb ^ (r & 7)) << 3)];
      }
#pragma unroll
      for (int mi = 0; mi < 4; ++mi)
#pragma unroll
        for (int ni = 0; ni < 4; ++ni)
          acc[mi][ni] = __builtin_amdgcn_mfma_f32_16x16x32_bf16(af[mi], bf[ni], acc[mi][ni], 0, 0, 0);
    }
  }

  if (INPLACE) {
    // Reads-done barrier among the 8 sibling units of this slot. Our K-loop
    // loads completed (consumed) before this point; siblings likewise before
    // their rdone increment -> WAR on h rows is safe after count reaches 8.
    __syncthreads();
    if (tid == 0) {
      ag_add(rdone + slot);
      while (ag_ld(rdone + slot) < 8) __builtin_amdgcn_s_sleep(1);
    }
    __syncthreads();
  }

  // Epilogue: relu -> bf16. C/D layout: col = lane&15, row = quad*4 + reg.
  const int pend = seg + cnt;
#pragma unroll
  for (int mi = 0; mi < 4; ++mi) {
#pragma unroll
    for (int ni = 0; ni < 4; ++ni) {
      const int col = n0 + wn + (ni << 4) + lr;
#pragma unroll
      for (int r4 = 0; r4 < 4; ++r4) {
        const int p = seg + m0 + wm + (mi << 4) + (quad << 2) + r4;
        if (p < pend) {
          float v = acc[mi][ni][r4];
          v = v > 0.f ? v : 0.f;
          O[(size_t)p * DIM + col] = f2bf(v);
        }
      }
    }
  }
}

// ---------------- persistent mega-kernel: prep -> GEMM1 -> GEMM2 -> combine --
// Work-queue design: any resident block can run any unit => deadlock-free at
// any achieved occupancy (spins only ever wait on units already claimed by
// resident, running blocks).
__global__ __launch_bounds__(256, 4)
void moe_mega_k(const float* __restrict__ x, const int* __restrict__ idx,
                const float* __restrict__ wts,
                const float* __restrict__ W1, const float* __restrict__ W2,
                float* __restrict__ out,
                int* ctr, int* counts, int* offsets, int* ntiles, int* tlist,
                int* bucket, int* pos,
                u16* xb, u16* w1b, u16* w2b, u16* h) {
  __shared__ u16 As[128 * 64];   // 16 KB
  __shared__ u16 Bs[128 * 64];   // 16 KB
  __shared__ int shq;
  __shared__ int lc[4][NEXP], lo[4][NEXP];

  int* qp    = ctr + 0;
  int* q1    = ctr + 1;
  int* q2    = ctr + 2;
  int* qc    = ctr + 3;
  int* g_xw1 = ctr + 4;    // target: 1 sort + 256 x + 256 W1 = 513
  int* g_w2  = ctr + 5;    // target: 256
  int* g2c   = ctr + 6;    // target: NGU
  int* done8 = ctr + 16;   // [136] GEMM1 units finished per slot
  int* rdone = ctr + 160;  // [136] GEMM2 sibling reads finished per slot

  const int tid = threadIdx.x;

  // ---------------- phase P: sort (unit 0) + bf16 casts (units 1..768) ------
  for (;;) {
    const int u = claim(qp, &shq);
    if (u >= PREP_UNITS) break;
    if (u == 0) {
      // ---- ballot sort, 4 waves, 64 items/lane over two passes ----
      const int w = tid >> 6, lane = tid & 63;
      const u64 ltmask = (lane == 63) ? 0x7fffffffffffffffull
                                      : ((1ull << lane) - 1);
      int cnt[NEXP] = {};
      for (int i = 0; i < 64; ++i) {
        const int e = idx[(w * 64 + i) * 64 + lane];
#pragma unroll
        for (int ex = 0; ex < NEXP; ++ex)
          cnt[ex] += (int)__popcll(__ballot(e == ex));
      }
      if (lane == 0) {
#pragma unroll
        for (int ex = 0; ex < NEXP; ++ex) lc[w][ex] = cnt[ex];
      }
      __syncthreads();
      if (tid == 0) {
        int s = 0; int c8[NEXP];
        for (int ex = 0; ex < NEXP; ++ex) {
          offsets[ex] = s; int c = 0;
          for (int ww = 0; ww < 4; ++ww) { lo[ww][ex] = s; s += lc[ww][ex]; c += lc[ww][ex]; }
          counts[ex] = c; c8[ex] = c;
        }
        int t = 0;  // round-robin: slot p -> expert p%8 while rounds full
        for (int r = 0; r < 128; ++r)
          for (int ex = 0; ex < NEXP; ++ex)
            if (r * 128 < c8[ex]) tlist[t++] = (r << 3) | ex;
        *ntiles = t;
      }
      __syncthreads();
      int cur[NEXP];
#pragma unroll
      for (int ex = 0; ex < NEXP; ++ex) cur[ex] = lo[w][ex];
      for (int i = 0; i < 64; ++i) {
        const int item = (w * 64 + i) * 64 + lane;
        const int e = idx[item];
        int p = 0;
#pragma unroll
        for (int ex = 0; ex < NEXP; ++ex) {
          u64 m = __ballot(e == ex);
          int rank = (int)__popcll(m & ltmask);
          if (e == ex) p = cur[ex] + rank;
          cur[ex] += (int)__popcll(m);
        }
        bucket[p] = item;
        pos[item] = p;
      }
      signal(g_xw1);
    } else {
      // ---- cast unit: 32768 elems of one region ----
      const int cu = u - 1;                       // 0..767
      const float* s = (cu < 256) ? x : (cu < 512) ? W1 : W2;
      u16* d = (cu < 256) ? xb : (cu < 512) ? w1b : w2b;
      const int b0 = (cu & 255) * 32768;
#pragma unroll 4
      for (int ii = 0; ii < 16; ++ii) {
        const int i = b0 + ii * 2048 + tid * 8;
        f32x4 a = *(const f32x4*)(s + i);
        f32x4 b = *(const f32x4*)(s + i + 4);
        short8 o;
        o[0] = (short)f2bf(a[0]); o[1] = (short)f2bf(a[1]);
        o[2] = (short)f2bf(a[2]); o[3] = (short)f2bf(a[3]);
        o[4] = (short)f2bf(b[0]); o[5] = (short)f2bf(b[1]);
        o[6] = (short)f2bf(b[2]); o[7] = (short)f2bf(b[3]);
        *(short8*)(d + i) = o;
      }
      signal((cu < 512) ? g_xw1 : g_w2);
    }
  }

  // ---------------- phase 1: GEMM1  h = relu(x[gather] @ W1^T) --------------
  gate_wait(g_xw1, 513);
  const int nt = *ntiles;
  for (;;) {
    const int u = claim(q1, &shq);
    if (u >= NGU) break;
    const int slot = u >> 3;              // slot-major: done8 fills early
    if (slot < nt) {
      gemm_unit<true, false>(slot, (u & 7) << 7, xb, w1b, h,
                             counts, offsets, bucket, tlist, nullptr, As, Bs);
      __threadfence();                    // release h stores
      __syncthreads();
      if (tid == 0) ag_add(done8 + slot);
    } else {
      if (tid == 0) ag_add(done8 + slot); // no-op unit still counts
    }
  }

  // ---------------- phase 2: GEMM2  y = relu(h @ W2^T), y over h ------------
  gate_wait(g_w2, 256);
  for (;;) {
    const int u = claim(q2, &shq);
    if (u >= NGU) break;
    const int slot = u >> 3;
    if (slot < nt) {
      if (tid == 0)                       // wait this slot's h complete
        while (ag_ld(done8 + slot) < 8) __builtin_amdgcn_s_sleep(1);
      __syncthreads();
      __threadfence();                    // acquire h
      gemm_unit<false, true>(slot, (u & 7) << 7, h, w2b, h,
                             counts, offsets, bucket, tlist, rdone, As, Bs);
      signal(g2c);
    } else {
      if (tid == 0) ag_add(g2c);
    }
  }

  // ---------------- phase 3: combine  out[t] = w0*y[p0] + w1*y[p1] ----------
  gate_wait(g2c, NGU);
  for (;;) {
    const int u = claim(qc, &shq);
    if (u >= COMB_UNITS) break;
    const int tb = u * 8;
#pragma unroll
    for (int pp = 0; pp < 4; ++pp) {
      const int t    = tb + pp * 2 + (tid >> 7);
      const int lane = tid & 127;
      const int col  = lane * 8;
      const int p0 = pos[2 * t], p1 = pos[2 * t + 1];
      const float w0 = wts[2 * t], w1 = wts[2 * t + 1];
      const short8 a = *(const short8*)(h + (size_t)p0 * DIM + col);
      const short8 b = *(const short8*)(h + (size_t)p1 * DIM + col);
      f32x4 o0, o1;
#pragma unroll
      for (int j = 0; j < 8; ++j) {
        float v = w0 * bf2f((u16)a[j]) + w1 * bf2f((u16)b[j]);
        if (j < 4) o0[j] = v; else o1[j - 4] = v;
      }
      float* op = out + (size_t)t * DIM + col;
      *(f32x4*)op = o0;
      *(f32x4*)(op + 4) = o1;
    }
  }
}

extern "C" void kernel_launch(void* const* d_in, const int* in_sizes, int n_in,
                              void* d_out, int out_size, void* d_ws, size_t ws_size,
                              hipStream_t stream) {
  const float* x   = (const float*)d_in[0];
  const int*   idx = (const int*)d_in[1];
  const float* wts = (const float*)d_in[2];
  const float* W1  = (const float*)d_in[3];
  const float* W2  = (const float*)d_in[4];
  float* out = (float*)d_out;

  char* ws = (char*)d_ws;
  // [0,2048): queue heads + gates + done8 + rdone  (zeroed every launch)
  int* ctr     = (int*)ws;
  // sort outputs (fully rewritten each launch; no zeroing needed)
  int* counts  = (int*)(ws + 2048);
  int* offsets = (int*)(ws + 2080);
  int* ntiles  = (int*)(ws + 2112);
  int* tlist   = (int*)(ws + 2176);
  int* bucket  = (int*)(ws + 8192);            // 64 KB
  int* pos     = (int*)(ws + 8192 + 65536);    // 64 KB
  const size_t base = 139264;                  // 16B-aligned
  u16* xb  = (u16*)(ws + base);                // 16 MB bf16 tokens
  u16* w1b = xb  + 8388608;                    // 16 MB
  u16* w2b = w1b + 8388608;                    // 16 MB
  u16* h   = w2b + 8388608;                    // 32 MB; y overwrites in place

  hipMemsetAsync(ctr, 0, 2048, stream);
  moe_mega_k<<<GRID_BLKS, 256, 0, stream>>>(x, idx, wts, W1, W2, out,
                                            ctr, counts, offsets, ntiles, tlist,
                                            bucket, pos, xb, w1b, w2b, h);
}

// Round 4
// 488.002 us; speedup vs baseline: 2.7664x; 2.7664x over previous
//
#include <hip/hip_runtime.h>

typedef unsigned short u16;
typedef unsigned int   u32;
typedef unsigned long long u64;
typedef __attribute__((ext_vector_type(8))) short short8;
typedef __attribute__((ext_vector_type(4))) float f32x4;

#define T_TOK 8192
#define DIM   1024
#define NEXP  8
#define NPAIR (T_TOK * 2)     // 16384 token-expert pairs
#define MAXTILES 136          // sum ceil(cnt_e/128) <= 135; 136 % 8 == 0
#define GATE_TGT 513          // 1 sort + 256 x-cast + 256 W1-cast

__device__ __forceinline__ u16 f2bf(float f) {
  u32 u = __builtin_bit_cast(u32, f);
  u32 r = (u + 0x7fffu + ((u >> 16) & 1u)) >> 16;  // RNE
  return (u16)r;
}

__device__ __forceinline__ void gl_lds16(const u16* g, u16* l) {
  __builtin_amdgcn_global_load_lds(
      (const __attribute__((address_space(1))) u32*)g,
      (__attribute__((address_space(3))) u32*)l,
      16, 0, 0);
}

// Agent(device)-scope atomics: cross-XCD visible (per-XCD L2s not coherent).
__device__ __forceinline__ int ag_add(int* p) {
  return __hip_atomic_fetch_add(p, 1, __ATOMIC_RELAXED, __HIP_MEMORY_SCOPE_AGENT);
}
__device__ __forceinline__ int ag_ld(int* p) {
  return __hip_atomic_load(p, __ATOMIC_RELAXED, __HIP_MEMORY_SCOPE_AGENT);
}
// Producer handoff: all threads flush stores (agent release), one bumps ctr.
__device__ __forceinline__ void signal(int* c) {
  __threadfence();
  __syncthreads();
  if (threadIdx.x == 0) ag_add(c);
}
// Consumer gate: wait for ctr, then acquire-fence before reading payloads.
__device__ __forceinline__ void gate_wait(int* c, int target) {
  if (threadIdx.x == 0)
    while (ag_ld(c) < target) __builtin_amdgcn_s_sleep(32);
  __syncthreads();
  __threadfence();
}

// ---------------- grouped GEMM unit: one 128x128 tile ------------------------
// Verified R0/R2 inner structure: 128x128x64 K-tiles, single-buffered 32KB LDS,
// XOR chunk swizzle (bank-conflict-free), global_load_lds width-16 staging,
// 16x16x32 bf16 MFMA, 4 waves (2x2), 4x4 frags.
// MODE 0 (GEMM1): A rows gathered via bucket (tokens), O = h, bf16 store.
// MODE 1 (GEMM2): A rows linear (sorted positions), epilogue fuses combine:
//   out[token] += wts[pair] * relu(v) via device-scope fp32 atomicAdd.
//   Each out cell is hit exactly K=2 times (zero contention).
template <int MODE>
__device__ void gemm_unit(int slot, int n0,
                          const u16* __restrict__ A, const u16* __restrict__ W,
                          u16* __restrict__ O, float* __restrict__ out,
                          const int* counts, const int* offsets,
                          const int* bucket, const int* tlist,
                          const float* wts, u16* As, u16* Bs) {
  const int info = tlist[slot];
  const int e    = info & 7;
  const int m0   = (info >> 3) << 7;
  const int cnt  = counts[e];
  const int seg  = offsets[e];

  const int tid  = threadIdx.x;
  const int lane = tid & 63;
  const int wave = tid >> 6;

  int aoff[4], boff[4];
#pragma unroll
  for (int j = 0; j < 4; ++j) {
    const int c   = ((wave << 2) + j) * 64 + lane;  // chunk 0..1023
    const int r   = c >> 3;                         // tile row
    const int c16 = (c & 7) ^ (r & 7);              // swizzled 16B chunk
    int p = seg + m0 + r;
    p = (p < seg + cnt) ? p : (seg + cnt - 1);      // clamp tail rows
    int rowbase;
    if (MODE == 0) { const int pair = bucket[p]; rowbase = (pair >> 1) * DIM; }
    else           { rowbase = p * DIM; }
    aoff[j] = rowbase + (c16 << 3);
    boff[j] = e * DIM * DIM + (n0 + r) * DIM + (c16 << 3);
  }

  f32x4 acc[4][4] = {};

  const int wm   = (wave >> 1) << 6;
  const int wn   = (wave & 1) << 6;
  const int lr   = lane & 15;
  const int quad = lane >> 4;

  for (int k0 = 0; k0 < DIM; k0 += 64) {
    __syncthreads();  // protect LDS reuse
#pragma unroll
    for (int j = 0; j < 4; ++j) {
      const int instr = (wave << 2) + j;
      gl_lds16(A + aoff[j] + k0, &As[instr << 9]);
      gl_lds16(W + boff[j] + k0, &Bs[instr << 9]);
    }
    __syncthreads();  // drains vmcnt for global_load_lds

#pragma unroll
    for (int kk = 0; kk < 64; kk += 32) {
      const int qb = (kk >> 3) + quad;
      short8 af[4], bf[4];
#pragma unroll
      for (int mi = 0; mi < 4; ++mi) {
        const int r = wm + (mi << 4) + lr;
        af[mi] = *(const short8*)&As[r * 64 + ((qb ^ (r & 7)) << 3)];
      }
#pragma unroll
      for (int ni = 0; ni < 4; ++ni) {
        const int r = wn + (ni << 4) + lr;
        bf[ni] = *(const short8*)&Bs[r * 64 + ((qb ^ (r & 7)) << 3)];
      }
#pragma unroll
      for (int mi = 0; mi < 4; ++mi)
#pragma unroll
        for (int ni = 0; ni < 4; ++ni)
          acc[mi][ni] = __builtin_amdgcn_mfma_f32_16x16x32_bf16(af[mi], bf[ni], acc[mi][ni], 0, 0, 0);
    }
  }

  // Epilogue. C/D layout: col = lane&15, row = quad*4 + reg.
  const int pend = seg + cnt;
#pragma unroll
  for (int mi = 0; mi < 4; ++mi) {
    if (MODE == 0) {
#pragma unroll
      for (int ni = 0; ni < 4; ++ni) {
        const int col = n0 + wn + (ni << 4) + lr;
#pragma unroll
        for (int r4 = 0; r4 < 4; ++r4) {
          const int p = seg + m0 + wm + (mi << 4) + (quad << 2) + r4;
          if (p < pend) {
            float v = acc[mi][ni][r4];
            v = v > 0.f ? v : 0.f;
            O[(size_t)p * DIM + col] = f2bf(v);
          }
        }
      }
    } else {
      bool  ok[4]; float wr[4]; int tr[4];
#pragma unroll
      for (int r4 = 0; r4 < 4; ++r4) {
        const int p = seg + m0 + wm + (mi << 4) + (quad << 2) + r4;
        ok[r4] = (p < pend);
        const int pair = ok[r4] ? bucket[p] : 0;
        wr[r4] = ok[r4] ? wts[pair] : 0.f;
        tr[r4] = pair >> 1;
      }
#pragma unroll
      for (int ni = 0; ni < 4; ++ni) {
        const int col = n0 + wn + (ni << 4) + lr;
#pragma unroll
        for (int r4 = 0; r4 < 4; ++r4) {
          if (ok[r4]) {
            float v = acc[mi][ni][r4];
            v = v > 0.f ? v : 0.f;
            __hip_atomic_fetch_add(out + (size_t)tr[r4] * DIM + col, wr[r4] * v,
                                   __ATOMIC_RELAXED, __HIP_MEMORY_SCOPE_AGENT);
          }
        }
      }
    }
  }
}

// ---------------- kernel 1: static prep + gate + GEMM1 -----------------------
// Grid (136, 8), linear block id b = bx + 136*by. STATIC prep assignment (R3
// lesson: dynamic claiming destroys expert->XCD pinning; everything here is
// static): b==0 sort; b in [1,768] casts (x, W1, W2: 256 units each);
// b in [769,896] zero `out` (for kernel2's atomic combine). Producers signal
// the gate BEFORE waiting on it -> deadlock-free at any dispatch order or
// residency. After gate: block runs its own GEMM1 tile (slot = bx, XCD-pinned
// since 136%8==0 and tlist is round-robin by expert).
__global__ __launch_bounds__(256, 4)
void prep_gemm1_k(const float* __restrict__ x, const int* __restrict__ idx,
                  const float* __restrict__ W1, const float* __restrict__ W2,
                  float* __restrict__ out,
                  int* ctr, int* counts, int* offsets, int* ntiles, int* tlist,
                  int* bucket,
                  u16* xb, u16* w1b, u16* w2b, u16* h) {
  __shared__ u16 As[128 * 64];   // 16 KB
  __shared__ u16 Bs[128 * 64];   // 16 KB
  __shared__ int lc[4][NEXP], lo[4][NEXP];

  int* gate = ctr;
  const int tid = threadIdx.x;
  const int b = (int)blockIdx.x + MAXTILES * (int)blockIdx.y;  // 0..1087

  if (b == 0) {
    // ---- ballot sort: 4 waves, 64 items/lane, two passes ----
    const int w = tid >> 6, lane = tid & 63;
    const u64 ltmask = (lane == 63) ? 0x7fffffffffffffffull
                                    : ((1ull << lane) - 1);
    int cnt[NEXP] = {};
    for (int i = 0; i < 64; ++i) {
      const int e = idx[(w * 64 + i) * 64 + lane];
#pragma unroll
      for (int ex = 0; ex < NEXP; ++ex)
        cnt[ex] += (int)__popcll(__ballot(e == ex));
    }
    if (lane == 0) {
#pragma unroll
      for (int ex = 0; ex < NEXP; ++ex) lc[w][ex] = cnt[ex];
    }
    __syncthreads();
    if (tid == 0) {
      int s = 0; int c8[NEXP];
      for (int ex = 0; ex < NEXP; ++ex) {
        offsets[ex] = s; int c = 0;
        for (int ww = 0; ww < 4; ++ww) { lo[ww][ex] = s; s += lc[ww][ex]; c += lc[ww][ex]; }
        counts[ex] = c; c8[ex] = c;
      }
      int t = 0;  // round-robin: slot p -> expert p%8 while rounds full
      for (int r = 0; r < 128; ++r)
        for (int ex = 0; ex < NEXP; ++ex)
          if (r * 128 < c8[ex]) tlist[t++] = (r << 3) | ex;
      *ntiles = t;
    }
    __syncthreads();
    int cur[NEXP];
#pragma unroll
    for (int ex = 0; ex < NEXP; ++ex) cur[ex] = lo[w][ex];
    for (int i = 0; i < 64; ++i) {
      const int item = (w * 64 + i) * 64 + lane;
      const int e = idx[item];
      int p = 0;
#pragma unroll
      for (int ex = 0; ex < NEXP; ++ex) {
        u64 m = __ballot(e == ex);
        int rank = (int)__popcll(m & ltmask);
        if (e == ex) p = cur[ex] + rank;
        cur[ex] += (int)__popcll(m);
      }
      bucket[p] = item;
    }
    signal(gate);
  } else if (b <= 768) {
    // ---- cast unit: 32768 fp32 elems of one region -> bf16 ----
    const int cu = b - 1;                       // 0..767
    const float* s = (cu < 256) ? x : (cu < 512) ? W1 : W2;
    u16* d = (cu < 256) ? xb : (cu < 512) ? w1b : w2b;
    const int b0 = (cu & 255) * 32768;
#pragma unroll 4
    for (int ii = 0; ii < 16; ++ii) {
      const int i = b0 + ii * 2048 + tid * 8;
      f32x4 a = *(const f32x4*)(s + i);
      f32x4 bb = *(const f32x4*)(s + i + 4);
      short8 o;
      o[0] = (short)f2bf(a[0]);  o[1] = (short)f2bf(a[1]);
      o[2] = (short)f2bf(a[2]);  o[3] = (short)f2bf(a[3]);
      o[4] = (short)f2bf(bb[0]); o[5] = (short)f2bf(bb[1]);
      o[6] = (short)f2bf(bb[2]); o[7] = (short)f2bf(bb[3]);
      *(short8*)(d + i) = o;
    }
    if (cu < 512) signal(gate);   // x and W1 gate GEMM1; W2 done by kernel end
  } else if (b <= 896) {
    // ---- zero `out` for kernel2's atomic combine: 64K floats each ----
    const int z = b - 769;                      // 0..127
    float* o0 = out + (size_t)z * 65536;
    const f32x4 zero = {0.f, 0.f, 0.f, 0.f};
    for (int ii = 0; ii < 64; ++ii)
      *(f32x4*)(o0 + ii * 1024 + tid * 4) = zero;
  }

  gate_wait(gate, GATE_TGT);
  const int nt = *ntiles;
  const int slot = (int)blockIdx.x;
  if (slot < nt)
    gemm_unit<0>(slot, (int)blockIdx.y << 7, xb, w1b, h, nullptr,
                 counts, offsets, bucket, tlist, nullptr, As, Bs);
}

// ---------------- kernel 2: GEMM2 with fused combine -------------------------
__global__ __launch_bounds__(256, 4)
void gemm2_comb_k(const u16* __restrict__ h, const u16* __restrict__ w2b,
                  const float* __restrict__ wts, float* __restrict__ out,
                  const int* counts, const int* offsets, const int* ntiles,
                  const int* tlist, const int* bucket) {
  __shared__ u16 As[128 * 64];
  __shared__ u16 Bs[128 * 64];
  const int slot = (int)blockIdx.x;
  if (slot >= *ntiles) return;
  gemm_unit<1>(slot, (int)blockIdx.y << 7, h, w2b, nullptr, out,
               counts, offsets, bucket, tlist, wts, As, Bs);
}

extern "C" void kernel_launch(void* const* d_in, const int* in_sizes, int n_in,
                              void* d_out, int out_size, void* d_ws, size_t ws_size,
                              hipStream_t stream) {
  const float* x   = (const float*)d_in[0];
  const int*   idx = (const int*)d_in[1];
  const float* wts = (const float*)d_in[2];
  const float* W1  = (const float*)d_in[3];
  const float* W2  = (const float*)d_in[4];
  float* out = (float*)d_out;

  char* ws = (char*)d_ws;
  int* ctr     = (int*)ws;                     // gate counter (zeroed/launch)
  int* counts  = (int*)(ws + 2048);
  int* offsets = (int*)(ws + 2080);
  int* ntiles  = (int*)(ws + 2112);
  int* tlist   = (int*)(ws + 2176);
  int* bucket  = (int*)(ws + 8192);            // 64 KB
  const size_t base = 139264;                  // 16B-aligned
  u16* xb  = (u16*)(ws + base);                // 16 MB bf16 tokens
  u16* w1b = xb  + 8388608;                    // 16 MB
  u16* w2b = w1b + 8388608;                    // 16 MB
  u16* h   = w2b + 8388608;                    // 32 MB

  hipMemsetAsync(ctr, 0, 64, stream);
  dim3 gg(MAXTILES, DIM / 128);  // (136, 8): bx = tile slot -> XCD = expert
  prep_gemm1_k<<<gg, 256, 0, stream>>>(x, idx, W1, W2, out,
                                       ctr, counts, offsets, ntiles, tlist,
                                       bucket, xb, w1b, w2b, h);
  gemm2_comb_k<<<gg, 256, 0, stream>>>(h, w2b, wts, out,
                                       counts, offsets, ntiles, tlist, bucket);
}

// Round 6
// 280.902 us; speedup vs baseline: 4.8059x; 1.7373x over previous
//
#include <hip/hip_runtime.h>

typedef unsigned short u16;
typedef unsigned int   u32;
typedef unsigned long long u64;
typedef __attribute__((ext_vector_type(8))) short short8;
typedef __attribute__((ext_vector_type(4))) float f32x4;

#define T_TOK 8192
#define DIM   1024
#define NEXP  8
#define NPAIR (T_TOK * 2)   // 16384 token-expert pairs
#define MAXTILES 136        // sum ceil(cnt_e/128) <= 135; 136 % 8 == 0

__device__ __forceinline__ u16 f2bf(float f) {
  u32 u = __builtin_bit_cast(u32, f);
  u32 r = (u + 0x7fffu + ((u >> 16) & 1u)) >> 16;  // RNE
  return (u16)r;
}

__device__ __forceinline__ void gl_lds16(const u16* g, u16* l) {
  __builtin_amdgcn_global_load_lds(
      (const __attribute__((address_space(1))) u32*)g,
      (__attribute__((address_space(3))) u32*)l,
      16, 0, 0);
}

// ---------------- fused prep: cast x/W1/W2 + zero out + pair sort ------------
// Block 0: single-block ballot sort (hides under the BW-bound cast stream —
// measured R1: fusing sort saved ~33us vs separate launch). Blocks 1..3072:
// fp32->bf16 cast. Blocks 3073..3200: zero `out` for GEMM2's atomic combine.
// R3/R4 lesson (twice-measured): NO in-kernel gates/fences — kernel boundaries
// are the cheap sync (~25us) vs device-scope handoff (~200us+ of stall).
__global__ void prep_k(const float* __restrict__ x, const float* __restrict__ W1,
                       const float* __restrict__ W2,
                       u16* __restrict__ xb, u16* __restrict__ w1b, u16* __restrict__ w2b,
                       float* __restrict__ out,
                       const int* __restrict__ idx,
                       int* __restrict__ counts, int* __restrict__ offsets,
                       int* __restrict__ bucket,
                       int* __restrict__ tlist, int* __restrict__ ntiles) {
  __shared__ int lc[16][NEXP];
  __shared__ int lo[16][NEXP];

  const int b = (int)blockIdx.x;
  if (b >= 1 && b <= 3072) {
    // ---- cast path: 3072 blocks x 1024 threads x 8 elems = 3 x 8388608 ----
    const int g = ((b - 1) * 1024 + (int)threadIdx.x) * 8;
    const int region = g >> 23;                      // 8388608 elems per region
    const int i = g & 0x7fffff;
    const float* s = (region == 0) ? x : (region == 1) ? W1 : W2;
    u16* d = (region == 0) ? xb : (region == 1) ? w1b : w2b;
    f32x4 a = *(const f32x4*)(s + i);
    f32x4 bb = *(const f32x4*)(s + i + 4);
    short8 o;
    o[0] = (short)f2bf(a[0]);  o[1] = (short)f2bf(a[1]);
    o[2] = (short)f2bf(a[2]);  o[3] = (short)f2bf(a[3]);
    o[4] = (short)f2bf(bb[0]); o[5] = (short)f2bf(bb[1]);
    o[6] = (short)f2bf(bb[2]); o[7] = (short)f2bf(bb[3]);
    *(short8*)(d + i) = o;
    return;
  }
  if (b > 3072) {
    // ---- zero out[]: 128 blocks x 65536 floats (re-zeroed every launch) ----
    float* o0 = out + (size_t)(b - 3073) * 65536;
    const f32x4 zero = {0.f, 0.f, 0.f, 0.f};
#pragma unroll
    for (int ii = 0; ii < 16; ++ii)
      *(f32x4*)(o0 + ii * 4096 + threadIdx.x * 4) = zero;
    return;
  }

  // ---- block 0: ballot sort, 16 waves, 16 items/lane, no atomics ----
  // Emits tlist ROUND-ROBIN over experts so tile-slot p has expert p%8,
  // enabling the expert->XCD L2-locality swizzle in the GEMM.
  const int tid  = threadIdx.x;
  const int w    = tid >> 6;
  const int lane = tid & 63;
  const u64 ltmask = (lane == 63) ? 0x7fffffffffffffffull : ((1ull << lane) - 1);

  int e_i[16];
#pragma unroll
  for (int i = 0; i < 16; ++i) e_i[i] = idx[(w * 16 + i) * 64 + lane];

  int cnt[NEXP] = {};
#pragma unroll
  for (int i = 0; i < 16; ++i) {
#pragma unroll
    for (int ex = 0; ex < NEXP; ++ex) {
      u64 m = __ballot(e_i[i] == ex);
      cnt[ex] += (int)__popcll(m);
    }
  }
  if (lane == 0) {
#pragma unroll
    for (int ex = 0; ex < NEXP; ++ex) lc[w][ex] = cnt[ex];
  }
  __syncthreads();

  if (tid == 0) {
    int s = 0;
    int c8[NEXP];
    for (int ex = 0; ex < NEXP; ++ex) {
      offsets[ex] = s;
      int c = 0;
      for (int ww = 0; ww < 16; ++ww) { lo[ww][ex] = s; s += lc[ww][ex]; c += lc[ww][ex]; }
      counts[ex] = c;
      c8[ex] = c;
    }
    int t = 0;  // round-robin emission: slot p -> expert p%8 while rounds full
    for (int r = 0; r < 128; ++r)
      for (int ex = 0; ex < NEXP; ++ex)
        if (r * 128 < c8[ex]) tlist[t++] = (r << 3) | ex;
    *ntiles = t;
  }
  __syncthreads();

  int cur[NEXP];
#pragma unroll
  for (int ex = 0; ex < NEXP; ++ex) cur[ex] = lo[w][ex];
#pragma unroll
  for (int i = 0; i < 16; ++i) {
    const int item = (w * 16 + i) * 64 + lane;
    const int e = e_i[i];
    int p = 0;
#pragma unroll
    for (int ex = 0; ex < NEXP; ++ex) {
      u64 m = __ballot(e == ex);
      int rank = (int)__popcll(m & ltmask);
      if (e == ex) p = cur[ex] + rank;
      cur[ex] += (int)__popcll(m);
    }
    bucket[p] = item;
  }
}

// ---------------- grouped GEMM: 128x128 tile, verified R2 inner loop ---------
// 128x128x64 K-tiles, single-buffered 32KB LDS, XOR chunk swizzle
// (bank-conflict-free, 2-way = free per m136), global_load_lds width-16
// staging, 16x16x32 bf16 MFMA, 4 waves (2x2), 4x4 frags. Grid (136, 8):
// blockIdx.x = tile slot, expert = slot%8 (round-robin tlist) -> XCD pinning
// since gridDim.x%8==0 (R3 lesson: this pinning is worth 6.6x on FETCH).
// __launch_bounds__(256,4): 124 combined VGPR+AGPR fits the 128/wave budget
// at 4 waves/SIMD (R1 lesson: 5 forces spill, 2x slowdown).
//
// MODE 0 (GEMM1): A rows gathered via bucket (token rows of xb); h = bf16.
// MODE 1 (GEMM2): A rows linear (sorted positions of h); epilogue fuses the
//   combine: out[token] += wts[pair] * relu(v) via device-scope atomicAdd.
//   Each out cell is hit exactly K=2 times -> zero contention; ordering vs
//   prep's zeroing and vs the harness read is by kernel boundaries (no fences).
template <int MODE>
__global__ __launch_bounds__(256, 4)
void moe_gemm_k(const u16* __restrict__ A,
                const u16* __restrict__ W,
                u16* __restrict__ O,
                float* __restrict__ out,
                const float* __restrict__ wts,
                const int* __restrict__ counts,
                const int* __restrict__ offsets,
                const int* __restrict__ bucket,
                const int* __restrict__ tlist,
                const int* __restrict__ ntiles) {
  if ((int)blockIdx.x >= *ntiles) return;
  const int info = tlist[blockIdx.x];
  const int e    = info & 7;
  const int m0   = (info >> 3) << 7;
  const int cnt  = counts[e];
  const int seg  = offsets[e];
  const int n0   = blockIdx.y << 7;

  __shared__ u16 As[128 * 64];  // 16 KB, row-major [r][64] with chunk swizzle
  __shared__ u16 Bs[128 * 64];  // 16 KB

  const int tid  = threadIdx.x;
  const int lane = tid & 63;
  const int wave = tid >> 6;

  // Staging: tile = 1024 chunks of 16B per matrix; wave issues 4 A + 4 B
  // global_load_lds per K-iter. Global chunk is XOR-swizzled by row.
  int aoff[4], boff[4];
#pragma unroll
  for (int j = 0; j < 4; ++j) {
    const int c   = ((wave << 2) + j) * 64 + lane;  // chunk 0..1023
    const int r   = c >> 3;                         // tile row
    const int c16 = (c & 7) ^ (r & 7);              // swizzled 16B chunk
    int p = seg + m0 + r;
    p = (p < seg + cnt) ? p : (seg + cnt - 1);      // clamp tail rows
    int rowbase;
    if (MODE == 0) { const int pair = bucket[p]; rowbase = (pair >> 1) * DIM; }
    else           { rowbase = p * DIM; }
    aoff[j] = rowbase + (c16 << 3);
    boff[j] = e * DIM * DIM + (n0 + r) * DIM + (c16 << 3);
  }

  f32x4 acc[4][4] = {};

  const int wm   = (wave >> 1) << 6;
  const int wn   = (wave & 1) << 6;
  const int lr   = lane & 15;
  const int quad = lane >> 4;

  for (int k0 = 0; k0 < DIM; k0 += 64) {
    __syncthreads();  // protect LDS reuse
#pragma unroll
    for (int j = 0; j < 4; ++j) {
      const int instr = (wave << 2) + j;
      gl_lds16(A + aoff[j] + k0, &As[instr << 9]);
      gl_lds16(W + boff[j] + k0, &Bs[instr << 9]);
    }
    __syncthreads();  // drains vmcnt for global_load_lds

#pragma unroll
    for (int kk = 0; kk < 64; kk += 32) {
      const int qb = (kk >> 3) + quad;  // wanted global chunk
      short8 af[4], bf[4];
#pragma unroll
      for (int mi = 0; mi < 4; ++mi) {
        const int r = wm + (mi << 4) + lr;
        af[mi] = *(const short8*)&As[r * 64 + ((qb ^ (r & 7)) << 3)];
      }
#pragma unroll
      for (int ni = 0; ni < 4; ++ni) {
        const int r = wn + (ni << 4) + lr;
        bf[ni] = *(const short8*)&Bs[r * 64 + ((qb ^ (r & 7)) << 3)];
      }
#pragma unroll
      for (int mi = 0; mi < 4; ++mi)
#pragma unroll
        for (int ni = 0; ni < 4; ++ni)
          acc[mi][ni] = __builtin_amdgcn_mfma_f32_16x16x32_bf16(af[mi], bf[ni], acc[mi][ni], 0, 0, 0);
    }
  }

  // Epilogue. C/D layout: col = lane&15, row = quad*4 + reg.
  const int pend = seg + cnt;
#pragma unroll
  for (int mi = 0; mi < 4; ++mi) {
    if (MODE == 0) {
#pragma unroll
      for (int ni = 0; ni < 4; ++ni) {
        const int col = n0 + wn + (ni << 4) + lr;
#pragma unroll
        for (int r4 = 0; r4 < 4; ++r4) {
          const int p = seg + m0 + wm + (mi << 4) + (quad << 2) + r4;
          if (p < pend) {
            float v = acc[mi][ni][r4];
            v = v > 0.f ? v : 0.f;
            O[(size_t)p * DIM + col] = f2bf(v);
          }
        }
      }
    } else {
      // Fused combine: hoist per-row routing (indep of ni).
      bool ok[4]; float wr[4]; int tr[4];
#pragma unroll
      for (int r4 = 0; r4 < 4; ++r4) {
        const int p = seg + m0 + wm + (mi << 4) + (quad << 2) + r4;
        ok[r4] = (p < pend);
        const int pair = ok[r4] ? bucket[p] : 0;
        wr[r4] = ok[r4] ? wts[pair] : 0.f;
        tr[r4] = pair >> 1;
      }
#pragma unroll
      for (int ni = 0; ni < 4; ++ni) {
        const int col = n0 + wn + (ni << 4) + lr;
#pragma unroll
        for (int r4 = 0; r4 < 4; ++r4) {
          if (ok[r4]) {
            float v = acc[mi][ni][r4];
            v = v > 0.f ? v : 0.f;
            __hip_atomic_fetch_add(out + (size_t)tr[r4] * DIM + col, wr[r4] * v,
                                   __ATOMIC_RELAXED, __HIP_MEMORY_SCOPE_AGENT);
          }
        }
      }
    }
  }
}

extern "C" void kernel_launch(void* const* d_in, const int* in_sizes, int n_in,
                              void* d_out, int out_size, void* d_ws, size_t ws_size,
                              hipStream_t stream) {
  const float* x   = (const float*)d_in[0];
  const int*   idx = (const int*)d_in[1];
  const float* wts = (const float*)d_in[2];
  const float* W1  = (const float*)d_in[3];
  const float* W2  = (const float*)d_in[4];
  float* out = (float*)d_out;

  char* ws = (char*)d_ws;
  int* counts  = (int*)ws;                       // 8
  int* offsets = (int*)(ws + 32);                // 8
  int* ntiles  = (int*)(ws + 64);                // 1
  int* tlist   = (int*)(ws + 128);               // <=136
  int* bucket  = (int*)(ws + 1024);              // 16384 ints
  const size_t base = 132096;                    // 16B-aligned
  const size_t MB16 = 16ull * 1024 * 1024;
  u16* xb  = (u16*)(ws + base);                  // 16 MB
  u16* w1b = (u16*)(ws + base + MB16);           // 16 MB
  u16* w2b = (u16*)(ws + base + 2 * MB16);       // 16 MB
  u16* h   = (u16*)(ws + base + 3 * MB16);       // 32 MB

  // 3 launches: prep -> GEMM1 -> GEMM2+combine (boundaries are the sync).
  prep_k<<<3201, 1024, 0, stream>>>(x, W1, W2, xb, w1b, w2b, out,
                                    idx, counts, offsets, bucket, tlist, ntiles);

  dim3 gg(MAXTILES, DIM / 128);  // (136, 8): x = tile slot -> XCD = expert
  moe_gemm_k<0><<<gg, 256, 0, stream>>>(xb, w1b, h, nullptr, nullptr,
                                        counts, offsets, bucket, tlist, ntiles);
  moe_gemm_k<1><<<gg, 256, 0, stream>>>(h, w2b, nullptr, out, wts,
                                        counts, offsets, bucket, tlist, ntiles);
}

// Round 7
// 262.800 us; speedup vs baseline: 5.1370x; 1.0689x over previous
//
#include <hip/hip_runtime.h>

typedef unsigned short u16;
typedef unsigned int   u32;
typedef unsigned long long u64;
typedef __attribute__((ext_vector_type(8))) short short8;
typedef __attribute__((ext_vector_type(4))) float f32x4;

#define T_TOK 8192
#define DIM   1024
#define NEXP  8
#define NPAIR (T_TOK * 2)   // 16384 token-expert pairs
#define MAXTILES 136        // sum ceil(cnt_e/128) <= 135; 136 % 8 == 0

__device__ __forceinline__ u16 f2bf(float f) {
  u32 u = __builtin_bit_cast(u32, f);
  u32 r = (u + 0x7fffu + ((u >> 16) & 1u)) >> 16;  // RNE
  return (u16)r;
}
__device__ __forceinline__ float bf2f(u16 b) {
  return __builtin_bit_cast(float, ((u32)b) << 16);
}

__device__ __forceinline__ void gl_lds16(const u16* g, u16* l) {
  __builtin_amdgcn_global_load_lds(
      (const __attribute__((address_space(1))) u32*)g,
      (__attribute__((address_space(3))) u32*)l,
      16, 0, 0);
}

// ---------------- fused prep: cast x/W1/W2 to bf16 + pair sort ---------------
// Block 0: single-block ballot sort (hides under the BW-bound cast stream).
// Blocks 1..3072: fp32->bf16 cast. R3/R4/R6 lessons: no gates, no atomics —
// kernel boundaries are the cheap sync.
__global__ void prep_k(const float* __restrict__ x, const float* __restrict__ W1,
                       const float* __restrict__ W2,
                       u16* __restrict__ xb, u16* __restrict__ w1b, u16* __restrict__ w2b,
                       const int* __restrict__ idx,
                       int* __restrict__ counts, int* __restrict__ offsets,
                       int* __restrict__ bucket, int* __restrict__ pos,
                       int* __restrict__ tlist, int* __restrict__ ntiles) {
  __shared__ int lc[16][NEXP];
  __shared__ int lo[16][NEXP];

  if (blockIdx.x != 0) {
    // ---- cast path: 3072 blocks x 1024 threads x 8 elems = 3 x 8388608 ----
    const int g = ((int)(blockIdx.x - 1) * 1024 + (int)threadIdx.x) * 8;
    const int region = g >> 23;                      // 8388608 elems per region
    const int i = g & 0x7fffff;
    const float* s = (region == 0) ? x : (region == 1) ? W1 : W2;
    u16* d = (region == 0) ? xb : (region == 1) ? w1b : w2b;
    f32x4 a = *(const f32x4*)(s + i);
    f32x4 b = *(const f32x4*)(s + i + 4);
    short8 o;
    o[0] = (short)f2bf(a[0]); o[1] = (short)f2bf(a[1]);
    o[2] = (short)f2bf(a[2]); o[3] = (short)f2bf(a[3]);
    o[4] = (short)f2bf(b[0]); o[5] = (short)f2bf(b[1]);
    o[6] = (short)f2bf(b[2]); o[7] = (short)f2bf(b[3]);
    *(short8*)(d + i) = o;
    return;
  }

  // ---- sort path: bucket pairs by expert, ballot-based, no atomics ----
  // Emits tlist ROUND-ROBIN over experts so tile-slot p has expert p%8,
  // enabling the expert->XCD L2-locality swizzle in the GEMM.
  const int tid  = threadIdx.x;
  const int w    = tid >> 6;
  const int lane = tid & 63;
  const u64 ltmask = (lane == 63) ? 0x7fffffffffffffffull : ((1ull << lane) - 1);

  int e_i[16];
#pragma unroll
  for (int i = 0; i < 16; ++i) e_i[i] = idx[(w * 16 + i) * 64 + lane];

  int cnt[NEXP] = {};
#pragma unroll
  for (int i = 0; i < 16; ++i) {
#pragma unroll
    for (int ex = 0; ex < NEXP; ++ex) {
      u64 m = __ballot(e_i[i] == ex);
      cnt[ex] += (int)__popcll(m);
    }
  }
  if (lane == 0) {
#pragma unroll
    for (int ex = 0; ex < NEXP; ++ex) lc[w][ex] = cnt[ex];
  }
  __syncthreads();

  if (tid == 0) {
    int s = 0;
    int c8[NEXP];
    for (int ex = 0; ex < NEXP; ++ex) {
      offsets[ex] = s;
      int c = 0;
      for (int ww = 0; ww < 16; ++ww) { lo[ww][ex] = s; s += lc[ww][ex]; c += lc[ww][ex]; }
      counts[ex] = c;
      c8[ex] = c;
    }
    int t = 0;  // round-robin emission: slot p -> expert p%8 while rounds full
    for (int r = 0; r < 128; ++r)
      for (int ex = 0; ex < NEXP; ++ex)
        if (r * 128 < c8[ex]) tlist[t++] = (r << 3) | ex;
    *ntiles = t;
  }
  __syncthreads();

  int cur[NEXP];
#pragma unroll
  for (int ex = 0; ex < NEXP; ++ex) cur[ex] = lo[w][ex];
#pragma unroll
  for (int i = 0; i < 16; ++i) {
    const int item = (w * 16 + i) * 64 + lane;
    const int e = e_i[i];
    int p = 0;
#pragma unroll
    for (int ex = 0; ex < NEXP; ++ex) {
      u64 m = __ballot(e == ex);
      int rank = (int)__popcll(m & ltmask);
      if (e == ex) p = cur[ex] + rank;
      cur[ex] += (int)__popcll(m);
    }
    bucket[p] = item;
    pos[item] = p;
  }
}

// ---------------- grouped GEMM: O[p] = relu(Arow[p] @ W[e]^T), bf16 ----------
// 128x128x64 K-tiles, XOR chunk-swizzled LDS (bank-conflict-free, 2-way free
// per m136), global_load_lds width-16 staging, 16x16x32 bf16 MFMA, 4 waves
// (2x2), 4x4 frags. Grid (136, 8): blockIdx.x = tile slot, expert = slot%8
// (round-robin tlist) -> XCD pinning since gridDim.x%8==0 (worth 6.6x on
// FETCH, R3 lesson).
//
// NEW vs R2 (T3-minimum pipeline, plain-HIP-safe): DOUBLE-BUFFERED LDS
// (2x32KB = 64KB -> 2 blocks/CU) with next-K-tile staging issued BEFORE the
// current tile's compute. One __syncthreads per K-step (vs two): its implicit
// vmcnt(0) now waits only for loads that had the whole MFMA phase in flight,
// removing the serial {issue -> drain} from the per-step critical path.
// Correctness is carried entirely by __syncthreads (no raw barriers):
//   WAR: stage(t+1) writes buf[cur^1], last read at t-1 before that barrier.
//   RAW: reads at t+1 hit buf staged at t, drained by t's barrier vmcnt(0).
template <int GATHER>
__global__ __launch_bounds__(256, 2)
void moe_gemm_k(const u16* __restrict__ A,
                const u16* __restrict__ W,
                u16* __restrict__ O,
                const int* __restrict__ counts,
                const int* __restrict__ offsets,
                const int* __restrict__ bucket,
                const int* __restrict__ tlist,
                const int* __restrict__ ntiles) {
  if ((int)blockIdx.x >= *ntiles) return;
  const int info = tlist[blockIdx.x];
  const int e    = info & 7;
  const int m0   = (info >> 3) << 7;
  const int cnt  = counts[e];
  const int seg  = offsets[e];
  const int n0   = blockIdx.y << 7;

  __shared__ u16 As[2][128 * 64];  // 2 x 16 KB, row-major [r][64], chunk swizzle
  __shared__ u16 Bs[2][128 * 64];  // 2 x 16 KB

  const int tid  = threadIdx.x;
  const int lane = tid & 63;
  const int wave = tid >> 6;

  // Staging: tile = 1024 chunks of 16B per matrix; wave issues 4 A + 4 B
  // global_load_lds per K-step. Global chunk is XOR-swizzled by row; LDS dest
  // is linear (wave-uniform base + lane*16, the gl_lds HW contract).
  int aoff[4], boff[4];
#pragma unroll
  for (int j = 0; j < 4; ++j) {
    const int c   = ((wave << 2) + j) * 64 + lane;  // chunk 0..1023
    const int r   = c >> 3;                         // tile row
    const int c16 = (c & 7) ^ (r & 7);              // swizzled 16B chunk
    int p = seg + m0 + r;
    p = (p < seg + cnt) ? p : (seg + cnt - 1);      // clamp tail rows
    int rowbase;
    if (GATHER) { const int pair = bucket[p]; rowbase = (pair >> 1) * DIM; }
    else        { rowbase = p * DIM; }
    aoff[j] = rowbase + (c16 << 3);
    boff[j] = e * DIM * DIM + (n0 + r) * DIM + (c16 << 3);
  }

  f32x4 acc[4][4] = {};

  const int wm   = (wave >> 1) << 6;
  const int wn   = (wave & 1) << 6;
  const int lr   = lane & 15;
  const int quad = lane >> 4;

  // Prologue: stage K-tile 0 into buf 0, drain, barrier.
#pragma unroll
  for (int j = 0; j < 4; ++j) {
    const int instr = (wave << 2) + j;
    gl_lds16(A + aoff[j], &As[0][instr << 9]);
    gl_lds16(W + boff[j], &Bs[0][instr << 9]);
  }
  __syncthreads();

  int curb = 0;
  for (int t = 0; t < DIM / 64; ++t) {
    // Issue next K-tile's loads FIRST (into the other buffer) — they fly
    // under this tile's ds_read+MFMA phase.
    if (t < DIM / 64 - 1) {
      const int k0 = (t + 1) << 6;
      const int nb = curb ^ 1;
#pragma unroll
      for (int j = 0; j < 4; ++j) {
        const int instr = (wave << 2) + j;
        gl_lds16(A + aoff[j] + k0, &As[nb][instr << 9]);
        gl_lds16(W + boff[j] + k0, &Bs[nb][instr << 9]);
      }
    }

    const u16* asb = &As[curb][0];
    const u16* bsb = &Bs[curb][0];
#pragma unroll
    for (int kk = 0; kk < 64; kk += 32) {
      const int qb = (kk >> 3) + quad;  // wanted global chunk
      short8 af[4], bf[4];
#pragma unroll
      for (int mi = 0; mi < 4; ++mi) {
        const int r = wm + (mi << 4) + lr;
        af[mi] = *(const short8*)&asb[r * 64 + ((qb ^ (r & 7)) << 3)];
      }
#pragma unroll
      for (int ni = 0; ni < 4; ++ni) {
        const int r = wn + (ni << 4) + lr;
        bf[ni] = *(const short8*)&bsb[r * 64 + ((qb ^ (r & 7)) << 3)];
      }
#pragma unroll
      for (int mi = 0; mi < 4; ++mi)
#pragma unroll
        for (int ni = 0; ni < 4; ++ni)
          acc[mi][ni] = __builtin_amdgcn_mfma_f32_16x16x32_bf16(af[mi], bf[ni], acc[mi][ni], 0, 0, 0);
    }

    if (t < DIM / 64 - 1) {
      __syncthreads();  // drains vmcnt(0): next buffer ready; this one free
      curb ^= 1;
    }
  }

  // Epilogue: relu -> bf16. C/D layout: col = lane&15, row = quad*4 + reg.
  const int pend = seg + cnt;
#pragma unroll
  for (int mi = 0; mi < 4; ++mi) {
#pragma unroll
    for (int ni = 0; ni < 4; ++ni) {
      const int col = n0 + wn + (ni << 4) + lr;
#pragma unroll
      for (int r4 = 0; r4 < 4; ++r4) {
        const int p = seg + m0 + wm + (mi << 4) + (quad << 2) + r4;
        if (p < pend) {
          float v = acc[mi][ni][r4];
          v = v > 0.f ? v : 0.f;
          O[(size_t)p * DIM + col] = f2bf(v);
        }
      }
    }
  }
}

// ---------------- combine: out[t] = w0*y[pos[2t]] + w1*y[pos[2t+1]] ----------
__global__ void combine_k(const u16* __restrict__ y, const int* __restrict__ pos,
                          const float* __restrict__ wts, float* __restrict__ out) {
  const int t    = blockIdx.x * 2 + (threadIdx.x >> 7);
  const int lane = threadIdx.x & 127;
  const int col  = lane * 8;
  const int p0 = pos[2 * t], p1 = pos[2 * t + 1];
  const float w0 = wts[2 * t], w1 = wts[2 * t + 1];
  const short8 a = *(const short8*)(y + (size_t)p0 * DIM + col);
  const short8 b = *(const short8*)(y + (size_t)p1 * DIM + col);
  f32x4 o0, o1;
#pragma unroll
  for (int j = 0; j < 8; ++j) {
    float v = w0 * bf2f((u16)a[j]) + w1 * bf2f((u16)b[j]);
    if (j < 4) o0[j] = v; else o1[j - 4] = v;
  }
  float* op = out + (size_t)t * DIM + col;
  *(f32x4*)op = o0;
  *(f32x4*)(op + 4) = o1;
}

extern "C" void kernel_launch(void* const* d_in, const int* in_sizes, int n_in,
                              void* d_out, int out_size, void* d_ws, size_t ws_size,
                              hipStream_t stream) {
  const float* x   = (const float*)d_in[0];
  const int*   idx = (const int*)d_in[1];
  const float* wts = (const float*)d_in[2];
  const float* W1  = (const float*)d_in[3];
  const float* W2  = (const float*)d_in[4];
  float* out = (float*)d_out;

  char* ws = (char*)d_ws;
  int* counts  = (int*)ws;                       // 8
  int* offsets = (int*)(ws + 32);                // 8
  int* ntiles  = (int*)(ws + 64);                // 1
  int* tlist   = (int*)(ws + 128);               // <=136
  int* bucket  = (int*)(ws + 1024);              // 16384
  int* pos     = (int*)(ws + 1024 + 4 * NPAIR);  // 16384
  const size_t base = 132096;                    // 16B-aligned
  const size_t MB16 = 16ull * 1024 * 1024;
  u16* xb  = (u16*)(ws + base);                  // 16 MB
  u16* w1b = (u16*)(ws + base + MB16);           // 16 MB
  u16* w2b = (u16*)(ws + base + 2 * MB16);       // 16 MB
  u16* h   = (u16*)(ws + base + 3 * MB16);       // 32 MB
  u16* yb  = xb;                                 // 32 MB, aliases xb+w1b (dead)

  // block 0 = sort (starts first, hides under the cast stream)
  prep_k<<<3 * 1024 + 1, 1024, 0, stream>>>(x, W1, W2, xb, w1b, w2b,
                                            idx, counts, offsets, bucket, pos,
                                            tlist, ntiles);

  dim3 gg(MAXTILES, DIM / 128);  // (136, 8): x = tile slot -> XCD = expert
  moe_gemm_k<1><<<gg, 256, 0, stream>>>(xb, w1b, h, counts, offsets, bucket, tlist, ntiles);
  moe_gemm_k<0><<<gg, 256, 0, stream>>>(h, w2b, yb, counts, offsets, bucket, tlist, ntiles);

  combine_k<<<T_TOK / 2, 256, 0, stream>>>(yb, pos, wts, out);
}

// Round 10
// 244.669 us; speedup vs baseline: 5.5177x; 1.0741x over previous
//
#include <hip/hip_runtime.h>

typedef unsigned short u16;
typedef unsigned int   u32;
typedef unsigned long long u64;
typedef __attribute__((ext_vector_type(8))) short short8;
typedef __attribute__((ext_vector_type(4))) float f32x4;

#define T_TOK 8192
#define DIM   1024
#define NEXP  8
#define NPAIR (T_TOK * 2)   // 16384 token-expert pairs
#define MAXTILES 136        // sum ceil(cnt_e/128) <= 128 + 7; 136 % 8 == 0

__device__ __forceinline__ u16 f2bf(float f) {
  u32 u = __builtin_bit_cast(u32, f);
  u32 r = (u + 0x7fffu + ((u >> 16) & 1u)) >> 16;  // RNE
  return (u16)r;
}
__device__ __forceinline__ float bf2f(u16 b) {
  return __builtin_bit_cast(float, ((u32)b) << 16);
}

__device__ __forceinline__ void gl_lds16(const u16* g, u16* l) {
  __builtin_amdgcn_global_load_lds(
      (const __attribute__((address_space(1))) u32*)g,
      (__attribute__((address_space(3))) u32*)l,
      16, 0, 0);
}

// ---------------- fused prep: cast x/W1/W2 to bf16 + pair sort ---------------
// Block 0 runs the single-block ballot sort; blocks 1..3072 stream the
// fp32->bf16 cast (1024 thr x 8 elems). The ~10us serial sort hides under the
// BW-bound cast (measured: saved ~33us of non-GEMM time vs separate launch).
// R3/R4/R6 lessons: no in-kernel gates, no dynamic claiming, no atomics —
// kernel boundaries are the cheap sync on this chip.
__global__ void prep_k(const float* __restrict__ x, const float* __restrict__ W1,
                       const float* __restrict__ W2,
                       u16* __restrict__ xb, u16* __restrict__ w1b, u16* __restrict__ w2b,
                       const int* __restrict__ idx,
                       int* __restrict__ counts, int* __restrict__ offsets,
                       int* __restrict__ bucket, int* __restrict__ pos,
                       int* __restrict__ tlist, int* __restrict__ ntiles) {
  __shared__ int lc[16][NEXP];
  __shared__ int lo[16][NEXP];

  if (blockIdx.x != 0) {
    // ---- cast path: 3072 blocks x 1024 threads x 8 elems = 3 x 8388608 ----
    const int g = ((int)(blockIdx.x - 1) * 1024 + (int)threadIdx.x) * 8;
    const int region = g >> 23;                      // 8388608 elems per region
    const int i = g & 0x7fffff;
    const float* s = (region == 0) ? x : (region == 1) ? W1 : W2;
    u16* d = (region == 0) ? xb : (region == 1) ? w1b : w2b;
    f32x4 a = *(const f32x4*)(s + i);
    f32x4 b = *(const f32x4*)(s + i + 4);
    short8 o;
    o[0] = (short)f2bf(a[0]); o[1] = (short)f2bf(a[1]);
    o[2] = (short)f2bf(a[2]); o[3] = (short)f2bf(a[3]);
    o[4] = (short)f2bf(b[0]); o[5] = (short)f2bf(b[1]);
    o[6] = (short)f2bf(b[2]); o[7] = (short)f2bf(b[3]);
    *(short8*)(d + i) = o;
    return;
  }

  // ---- sort path: bucket pairs by expert, ballot-based, no atomics ----
  // Emits tlist ROUND-ROBIN over experts so tile-slot p has expert p%8,
  // enabling the expert->XCD L2-locality swizzle in the GEMM.
  const int tid  = threadIdx.x;
  const int w    = tid >> 6;
  const int lane = tid & 63;
  const u64 ltmask = (lane == 63) ? 0x7fffffffffffffffull : ((1ull << lane) - 1);

  int e_i[16];
#pragma unroll
  for (int i = 0; i < 16; ++i) e_i[i] = idx[(w * 16 + i) * 64 + lane];

  int cnt[NEXP] = {};
#pragma unroll
  for (int i = 0; i < 16; ++i) {
#pragma unroll
    for (int ex = 0; ex < NEXP; ++ex) {
      u64 m = __ballot(e_i[i] == ex);
      cnt[ex] += (int)__popcll(m);
    }
  }
  if (lane == 0) {
#pragma unroll
    for (int ex = 0; ex < NEXP; ++ex) lc[w][ex] = cnt[ex];
  }
  __syncthreads();

  if (tid == 0) {
    int s = 0;
    int c8[NEXP];
    for (int ex = 0; ex < NEXP; ++ex) {
      offsets[ex] = s;
      int c = 0;
      for (int ww = 0; ww < 16; ++ww) { lo[ww][ex] = s; s += lc[ww][ex]; c += lc[ww][ex]; }
      counts[ex] = c;
      c8[ex] = c;
    }
    int t = 0;  // round-robin emission: slot p -> expert p%8 while rounds full
    for (int r = 0; r < 128; ++r)
      for (int ex = 0; ex < NEXP; ++ex)
        if (r * 128 < c8[ex]) tlist[t++] = (r << 3) | ex;
    *ntiles = t;
  }
  __syncthreads();

  int cur[NEXP];
#pragma unroll
  for (int ex = 0; ex < NEXP; ++ex) cur[ex] = lo[w][ex];
#pragma unroll
  for (int i = 0; i < 16; ++i) {
    const int item = (w * 16 + i) * 64 + lane;
    const int e = e_i[i];
    int p = 0;
#pragma unroll
    for (int ex = 0; ex < NEXP; ++ex) {
      u64 m = __ballot(e == ex);
      int rank = (int)__popcll(m & ltmask);
      if (e == ex) p = cur[ex] + rank;
      cur[ex] += (int)__popcll(m);
    }
    bucket[p] = item;
    pos[item] = p;
  }
}

// ---------------- grouped GEMM: O[p] = relu(Arow[p] @ W[e]^T), bf16 ----------
// 128x128x64 K-tiles, single-buffered 32KB LDS, XOR-swizzled layout
// (bank-conflict-free), global_load_lds width-16 staging, 16x16x32 bf16 MFMA,
// 4 waves (2x2), 4x4 frags. Grid (MAXTILES, 8): blockIdx.x = tile slot,
// expert = slot%8 (round-robin tlist) -> XCD pinning since gridDim.x%8==0
// (R3 lesson: this pinning is worth 6.6x on FETCH).
//
// __launch_bounds__(256, 4): 4 blocks/CU = 1024 slots; 1088 blocks pack at
// 94%. Register check: ~60 VGPR + 64 AGPR = 124 <= 128/wave budget at 4
// waves/SIMD -> no spill (R1 lesson: 5/CU forces spill, 2x slowdown; R7
// lesson: 2/CU dbuf loses TLP > gains ILP).
//
// Swizzle: tile row r holds its 8 16B-chunks permuted by XOR(r&7). Staging
// lane loads global chunk (c&7)^(r&7) into linear LDS chunk c; fragment read
// of global chunk q reads LDS chunk q^(r&7). Each 16-lane ds_read_b128 group
// then covers all 32 banks exactly 2x (2-way = free, m136).
template <int GATHER>
__global__ __launch_bounds__(256, 4)
void moe_gemm_k(const u16* __restrict__ A,
                const u16* __restrict__ W,
                u16* __restrict__ O,
                const int* __restrict__ counts,
                const int* __restrict__ offsets,
                const int* __restrict__ bucket,
                const int* __restrict__ tlist,
                const int* __restrict__ ntiles) {
  if ((int)blockIdx.x >= *ntiles) return;
  const int info = tlist[blockIdx.x];
  const int e    = info & 7;
  const int m0   = (info >> 3) << 7;
  const int cnt  = counts[e];
  const int seg  = offsets[e];
  const int n0   = blockIdx.y << 7;

  __shared__ u16 As[128 * 64];  // 16 KB, row-major [r][64] with chunk swizzle
  __shared__ u16 Bs[128 * 64];  // 16 KB

  const int tid  = threadIdx.x;
  const int lane = tid & 63;
  const int wave = tid >> 6;

  // Staging: tile = 1024 chunks of 16B per matrix; wave issues 4 A + 4 B
  // global_load_lds per K-iter. Global chunk is XOR-swizzled by row.
  int aoff[4], boff[4];
#pragma unroll
  for (int j = 0; j < 4; ++j) {
    const int c   = ((wave << 2) + j) * 64 + lane;  // chunk 0..1023
    const int r   = c >> 3;                         // tile row
    const int c16 = (c & 7) ^ (r & 7);              // swizzled 16B chunk
    int p = seg + m0 + r;
    p = (p < seg + cnt) ? p : (seg + cnt - 1);      // clamp tail rows
    int rowbase;
    if (GATHER) { const int pair = bucket[p]; rowbase = (pair >> 1) * DIM; }
    else        { rowbase = p * DIM; }
    aoff[j] = rowbase + (c16 << 3);
    boff[j] = e * DIM * DIM + (n0 + r) * DIM + (c16 << 3);
  }

  f32x4 acc[4][4] = {};

  const int wm   = (wave >> 1) << 6;
  const int wn   = (wave & 1) << 6;
  const int lr   = lane & 15;
  const int quad = lane >> 4;

  for (int k0 = 0; k0 < DIM; k0 += 64) {
    __syncthreads();  // protect LDS reuse
#pragma unroll
    for (int j = 0; j < 4; ++j) {
      const int instr = (wave << 2) + j;
      gl_lds16(A + aoff[j] + k0, &As[instr << 9]);
      gl_lds16(W + boff[j] + k0, &Bs[instr << 9]);
    }
    __syncthreads();  // drains vmcnt for global_load_lds

#pragma unroll
    for (int kk = 0; kk < 64; kk += 32) {
      const int qb = (kk >> 3) + quad;  // wanted global chunk
      short8 af[4], bf[4];
#pragma unroll
      for (int mi = 0; mi < 4; ++mi) {
        const int r = wm + (mi << 4) + lr;
        af[mi] = *(const short8*)&As[r * 64 + ((qb ^ (r & 7)) << 3)];
      }
#pragma unroll
      for (int ni = 0; ni < 4; ++ni) {
        const int r = wn + (ni << 4) + lr;
        bf[ni] = *(const short8*)&Bs[r * 64 + ((qb ^ (r & 7)) << 3)];
      }
#pragma unroll
      for (int mi = 0; mi < 4; ++mi)
#pragma unroll
        for (int ni = 0; ni < 4; ++ni)
          acc[mi][ni] = __builtin_amdgcn_mfma_f32_16x16x32_bf16(af[mi], bf[ni], acc[mi][ni], 0, 0, 0);
    }
  }

  // Epilogue: relu -> bf16. C/D layout: col = lane&15, row = quad*4 + reg.
  const int pend = seg + cnt;
#pragma unroll
  for (int mi = 0; mi < 4; ++mi) {
#pragma unroll
    for (int ni = 0; ni < 4; ++ni) {
      const int col = n0 + wn + (ni << 4) + lr;
#pragma unroll
      for (int r4 = 0; r4 < 4; ++r4) {
        const int p = seg + m0 + wm + (mi << 4) + (quad << 2) + r4;
        if (p < pend) {
          float v = acc[mi][ni][r4];
          v = v > 0.f ? v : 0.f;
          O[(size_t)p * DIM + col] = f2bf(v);
        }
      }
    }
  }
}

// ---------------- combine: out[t] = w0*y[pos[2t]] + w1*y[pos[2t+1]] ----------
__global__ void combine_k(const u16* __restrict__ y, const int* __restrict__ pos,
                          const float* __restrict__ wts, float* __restrict__ out) {
  const int t    = blockIdx.x * 2 + (threadIdx.x >> 7);
  const int lane = threadIdx.x & 127;
  const int col  = lane * 8;
  const int p0 = pos[2 * t], p1 = pos[2 * t + 1];
  const float w0 = wts[2 * t], w1 = wts[2 * t + 1];
  const short8 a = *(const short8*)(y + (size_t)p0 * DIM + col);
  const short8 b = *(const short8*)(y + (size_t)p1 * DIM + col);
  f32x4 o0, o1;
#pragma unroll
  for (int j = 0; j < 8; ++j) {
    float v = w0 * bf2f((u16)a[j]) + w1 * bf2f((u16)b[j]);
    if (j < 4) o0[j] = v; else o1[j - 4] = v;
  }
  float* op = out + (size_t)t * DIM + col;
  *(f32x4*)op = o0;
  *(f32x4*)(op + 4) = o1;
}

extern "C" void kernel_launch(void* const* d_in, const int* in_sizes, int n_in,
                              void* d_out, int out_size, void* d_ws, size_t ws_size,
                              hipStream_t stream) {
  const float* x   = (const float*)d_in[0];
  const int*   idx = (const int*)d_in[1];
  const float* wts = (const float*)d_in[2];
  const float* W1  = (const float*)d_in[3];
  const float* W2  = (const float*)d_in[4];
  float* out = (float*)d_out;

  char* ws = (char*)d_ws;
  int* counts  = (int*)ws;                       // 8
  int* offsets = (int*)(ws + 32);                // 8
  int* ntiles  = (int*)(ws + 64);                // 1
  int* tlist   = (int*)(ws + 128);               // <=136
  int* bucket  = (int*)(ws + 1024);              // 16384
  int* pos     = (int*)(ws + 1024 + 4 * NPAIR);  // 16384
  const size_t base = 132096;                    // 16B-aligned
  const size_t MB16 = 16ull * 1024 * 1024;
  u16* xb  = (u16*)(ws + base);                  // 16 MB
  u16* w1b = (u16*)(ws + base + MB16);           // 16 MB
  u16* w2b = (u16*)(ws + base + 2 * MB16);       // 16 MB
  u16* h   = (u16*)(ws + base + 3 * MB16);       // 32 MB
  u16* yb  = xb;                                 // 32 MB, aliases xb+w1b (dead)

  // block 0 = sort (starts first, hides under the cast stream)
  prep_k<<<3 * 1024 + 1, 1024, 0, stream>>>(x, W1, W2, xb, w1b, w2b,
                                            idx, counts, offsets, bucket, pos,
                                            tlist, ntiles);

  dim3 gg(MAXTILES, DIM / 128);  // (136, 8): x = tile slot -> XCD = expert
  moe_gemm_k<1><<<gg, 256, 0, stream>>>(xb, w1b, h, counts, offsets, bucket, tlist, ntiles);
  moe_gemm_k<0><<<gg, 256, 0, stream>>>(h, w2b, yb, counts, offsets, bucket, tlist, ntiles);

  combine_k<<<T_TOK / 2, 256, 0, stream>>>(yb, pos, wts, out);
}